// Round 14
// baseline (288.408 us; speedup 1.0000x reference)
//
#include <hip/hip_runtime.h>
#include <hip/hip_bf16.h>

#define B_    2
#define T_    2048
#define D_    1024
#define H_    16
#define DK_   64
#define BH_   (B_*H_)
#define M_    (B_*T_)        // 4096 GEMM rows
#define NSTEP 5
#define DT_   0.1f
#define TWO_PI_F 6.28318530717958647692f
#define JROWS 8
#define LOG2E_F 1.44269504088896340736f

typedef __attribute__((ext_vector_type(8))) short s16x8;   // 8 bf16 (4 VGPRs)
typedef __attribute__((ext_vector_type(4))) float f32x4;
typedef __attribute__((ext_vector_type(2))) float f32x2;

__device__ __forceinline__ unsigned short f2bf(float f) {
  unsigned int u = __float_as_uint(f);
  u += 0x7FFFu + ((u >> 16) & 1u);       // round-to-nearest-even
  return (unsigned short)(u >> 16);
}

__device__ __forceinline__ void gload_lds16(const void* g, void* l) {
  __builtin_amdgcn_global_load_lds(
      (const __attribute__((address_space(1))) unsigned int*)g,
      (__attribute__((address_space(3))) unsigned int*)l, 16, 0, 0);
}

// ---------------------------------------------------------------------------
// f32 -> bf16 conversion, all 5 tensors in one launch.
// ---------------------------------------------------------------------------
__device__ __forceinline__ void conv8(const float* in, unsigned short* out, int i) {
  const float4* p = (const float4*)in + (size_t)i*2;
  float4 a = p[0], b = p[1];
  s16x8 o;
  o[0]=(short)f2bf(a.x); o[1]=(short)f2bf(a.y); o[2]=(short)f2bf(a.z); o[3]=(short)f2bf(a.w);
  o[4]=(short)f2bf(b.x); o[5]=(short)f2bf(b.y); o[6]=(short)f2bf(b.z); o[7]=(short)f2bf(b.w);
  *(s16x8*)(out + (size_t)i*8) = o;
}

__global__ void conv_all(const float* __restrict__ x,
                         const float* __restrict__ wq, const float* __restrict__ wk,
                         const float* __restrict__ wv, const float* __restrict__ wo,
                         unsigned short* __restrict__ xb,
                         unsigned short* __restrict__ oq, unsigned short* __restrict__ ok,
                         unsigned short* __restrict__ ov, unsigned short* __restrict__ oo)
{
  int bid = blockIdx.x;
  if (bid < 2048) {                       // x: 4M elements
    conv8(x, xb, bid*256 + threadIdx.x);
  } else {                                // weights: 1M each, 512 blocks each
    int r = bid - 2048;
    int z = r >> 9, lb = r & 511;
    const float* in = (z==0)?wq:(z==1)?wk:(z==2)?wv:wo;
    unsigned short* out = (z==0)?oq:(z==1)?ok:(z==2)?ov:oo;
    conv8(in, out, lb*256 + threadIdx.x);
  }
}

// ---------------------------------------------------------------------------
// bf16 GEMM (m97 structure): BMx128 tile, BK=64, 4 waves, global_load_lds(16B),
// XOR-swizzled LDS (linear dest + pre-swizzled global src + swizzled ds_read).
// Y[m,n] = sum_k A[m,k]*W[n,k].  MODE 0: bf16(Y*scale). MODE 2: f32(Y)+res.
// ---------------------------------------------------------------------------
template<int BM, int MODE>
__device__ __forceinline__ void gemm_body(const unsigned short* __restrict__ A,
    const unsigned short* __restrict__ W, void* __restrict__ outp,
    const float* __restrict__ res, float scale, int m0, int n0)
{
  constexpr int MF = BM/32;               // fragment rows per wave
  __shared__ unsigned short lA[BM*64];
  __shared__ unsigned short lB[128*64];
  const int t = threadIdx.x, wv = t >> 6, lane = t & 63;
  const int wm = wv >> 1, wn = wv & 1;
  const int lr = lane & 15, kg = lane >> 4;
  const int lrow = lane >> 3, sch = (lane & 7) ^ lrow;   // src pre-swizzle

  f32x4 acc[MF][4];
#pragma unroll
  for (int i = 0; i < MF; ++i)
#pragma unroll
    for (int j = 0; j < 4; ++j) { acc[i][j][0]=0.f; acc[i][j][1]=0.f; acc[i][j][2]=0.f; acc[i][j][3]=0.f; }

  for (int kt = 0; kt < 1024; kt += 64) {
#pragma unroll
    for (int ii = 0; ii < BM/32; ++ii) {
      const int inst = wv*(BM/32) + ii;
      const int row  = inst*8 + lrow;
      gload_lds16(A + (size_t)(m0+row)*1024 + kt + sch*8, lA + inst*512);
    }
#pragma unroll
    for (int ii = 0; ii < 4; ++ii) {
      const int inst = wv*4 + ii;
      const int row  = inst*8 + lrow;
      gload_lds16(W + (size_t)(n0+row)*1024 + kt + sch*8, lB + inst*512);
    }
    __syncthreads();

    s16x8 a0[MF], a1[MF], b0[4], b1[4];
#pragma unroll
    for (int mf = 0; mf < MF; ++mf) {
      int row = wm*(BM/2) + mf*16 + lr, s7 = row & 7;
      a0[mf] = *(const s16x8*)(lA + row*64 + ((kg^s7)*8));
      a1[mf] = *(const s16x8*)(lA + row*64 + (((kg+4)^s7)*8));
    }
#pragma unroll
    for (int nf = 0; nf < 4; ++nf) {
      int row = wn*64 + nf*16 + lr, s7 = row & 7;
      b0[nf] = *(const s16x8*)(lB + row*64 + ((kg^s7)*8));
      b1[nf] = *(const s16x8*)(lB + row*64 + (((kg+4)^s7)*8));
    }
#pragma unroll
    for (int mf = 0; mf < MF; ++mf)
#pragma unroll
      for (int nf = 0; nf < 4; ++nf) {
        acc[mf][nf] = __builtin_amdgcn_mfma_f32_16x16x32_bf16(a0[mf], b0[nf], acc[mf][nf], 0,0,0);
        acc[mf][nf] = __builtin_amdgcn_mfma_f32_16x16x32_bf16(a1[mf], b1[nf], acc[mf][nf], 0,0,0);
      }
    __syncthreads();
  }

#pragma unroll
  for (int mf = 0; mf < MF; ++mf)
#pragma unroll
    for (int nf = 0; nf < 4; ++nf)
#pragma unroll
      for (int r = 0; r < 4; ++r) {
        int grow = m0 + wm*(BM/2) + mf*16 + kg*4 + r;   // C/D: row=(lane>>4)*4+reg
        int gcol = n0 + wn*64 + nf*16 + lr;             //      col=lane&15
        size_t o = (size_t)grow*1024 + gcol;
        float v = acc[mf][nf][r];
        if (MODE == 0) ((unsigned short*)outp)[o] = f2bf(v*scale);
        else           ((float*)outp)[o] = v + res[o];
      }
}

__global__ __launch_bounds__(256)
void gemm_qkv(const unsigned short* __restrict__ xb,
              const unsigned short* __restrict__ wq, const unsigned short* __restrict__ wk,
              const unsigned short* __restrict__ wv_,
              unsigned short* __restrict__ Qb, unsigned short* __restrict__ Kb,
              unsigned short* __restrict__ Vb)
{
  const int z = blockIdx.z;
  const unsigned short* W = (z==0)?wq:((z==1)?wk:wv_);
  unsigned short* O = (z==0)?Qb:((z==1)?Kb:Vb);
  // z==0: Q pre-scaled by (1/8)*log2(e) so build_t can use exp2f directly.
  const float scale = (z==0) ? 0.125f*LOG2E_F : 1.0f;
  gemm_body<128,0>(xb, W, O, nullptr, scale, blockIdx.x*128, blockIdx.y*128);
}

__global__ __launch_bounds__(256)
void gemm_o(const unsigned short* __restrict__ Ab, const unsigned short* __restrict__ wo,
            float* __restrict__ out, const float* __restrict__ x)
{
  gemm_body<64,2>(Ab, wo, out, x, 1.0f, blockIdx.x*64, blockIdx.y*128);
}

// ---------------------------------------------------------------------------
// v01: exact f32 dot products, coalesced (k on lane axis) — r13, confirmed.
// ---------------------------------------------------------------------------
__global__ __launch_bounds__(256)
void v01_kernel(const float* __restrict__ x, const float* __restrict__ Wv,
                float* __restrict__ V01)
{
  const int wv = threadIdx.x >> 6, lane = threadIdx.x & 63;
  const int row = blockIdx.x*4 + wv;
  const float4* xr = (const float4*)(x + (size_t)row*1024);
  float4 xv[4];
#pragma unroll
  for (int p = 0; p < 4; ++p) xv[p] = xr[lane + p*64];

  float part[32];
#pragma unroll
  for (int c = 0; c < 32; ++c) {
    const int wcol = (c >> 1)*DK_ + (c & 1);
    const float4* wr = (const float4*)(Wv + (size_t)wcol*1024);
    float a = 0.f;
#pragma unroll
    for (int p = 0; p < 4; ++p) {
      float4 bv = wr[lane + p*64];
      a += xv[p].x*bv.x + xv[p].y*bv.y + xv[p].z*bv.z + xv[p].w*bv.w;
    }
    part[c] = a;
  }
#pragma unroll
  for (int c = 0; c < 32; ++c)
#pragma unroll
    for (int m = 1; m < 64; m <<= 1)
      part[c] += __shfl_xor(part[c], m);

  float outv = part[0];
#pragma unroll
  for (int c = 1; c < 32; ++c)
    if ((lane & 31) == c) outv = part[c];
  if (lane < 32) V01[(size_t)row*32 + lane] = outv;
}

// phase init + exact cos/sin (cos(atan2(a,c)) = c/r, sin = a/r)
__global__ void phase_init2(const float* __restrict__ V01, float* __restrict__ ph,
                            float* __restrict__ cw, float* __restrict__ sw)
{
  int idx = blockIdx.x*256 + threadIdx.x;  // over B*H*T
  int tt = idx & (T_-1);
  int bh = idx >> 11;
  int b = bh >> 4, h = bh & 15;
  float a = V01[((size_t)(b*T_ + tt))*32 + h*2 + 0];
  float c = V01[((size_t)(b*T_ + tt))*32 + h*2 + 1] + 1e-8f;
  ph[idx] = atan2f(a, c);
  float r = fmaxf(sqrtf(a*a + c*c), 1e-30f);
  cw[idx] = c / r;
  sw[idx] = a / r;
}

// ---------------------------------------------------------------------------
// build_t: one-shot J = fp8(exp(q.k/8)) with LDS-transposed fat stores +
// fused step-1 C/S/E (r11/r13 confirmed).  r14 deltas:
//  - LDS 35840 -> 32768 (lRed moved into dead lQ region) => 5 blocks/CU
//    (was 4; 5*32768 = exactly 160 KB).
//  - Q pre-scaled by log2e in gemm_qkv => exp2f (bare v_exp_f32), -64 vmul.
//  - C/S/E accumulated as f32x2 (v_pk_fma_f32): 6 VALU per (ti,s), was 12.
// ---------------------------------------------------------------------------
__global__ __launch_bounds__(256)
void build_t(const unsigned short* __restrict__ Qb, const unsigned short* __restrict__ Kb,
             unsigned char* __restrict__ J,
             const float* __restrict__ cr, const float* __restrict__ sr,
             float* __restrict__ parts)
{
  __shared__ unsigned char lds[32768];
  unsigned short* lK = (unsigned short*)lds;             // phase A: 16 KB
  unsigned short* lQ = (unsigned short*)(lds + 16384);   // phase A: 16 KB
  unsigned char*  lJ = lds;                              // phase B: 16 KB
  float* lRed = (float*)(lds + 16384);                   // phase B: 3 KB (in dead lQ)

  const int ib = blockIdx.x, jb = blockIdx.y, bh = blockIdx.z;
  const int b = bh >> 4, h = bh & 15;
  const int t = threadIdx.x, wv = t >> 6, lane = t & 63;
  const int wj = wv >> 1, wi = wv & 1;
  const int lr = lane & 15, kg = lane >> 4;
  const int lrow = lane >> 3, sch = (lane & 7) ^ lrow;   // src pre-swizzle
  const int i0 = ib*128;

  const unsigned short* Kbase = Kb + (size_t)b*T_*D_ + h*DK_;
  const unsigned short* Qbase = Qb + (size_t)b*T_*D_ + h*DK_;

  // ---- phase A: stage K (j-tile) and Q (i-tile)
#pragma unroll
  for (int ii = 0; ii < 4; ++ii) {
    const int inst = wv*4 + ii;
    const int row  = inst*8 + lrow;
    gload_lds16(Kbase + (size_t)(jb*128 + row)*D_ + sch*8, lK + inst*512);
    gload_lds16(Qbase + (size_t)(i0 + row)*D_ + sch*8, lQ + inst*512);
  }
  __syncthreads();

  // all fragment reads upfront (LDS freed for reuse after next barrier)
  s16x8 ak0[4], ak1[4], bq0[4], bq1[4];
#pragma unroll
  for (int s = 0; s < 4; ++s) {
    int row = wj*64 + s*16 + lr, s7 = row & 7;
    ak0[s] = *(const s16x8*)(lK + row*64 + ((kg^s7)*8));
    ak1[s] = *(const s16x8*)(lK + row*64 + (((kg+4)^s7)*8));
  }
#pragma unroll
  for (int ti = 0; ti < 4; ++ti) {
    int row = wi*64 + ti*16 + lr, s7 = row & 7;
    bq0[ti] = *(const s16x8*)(lQ + row*64 + ((kg^s7)*8));
    bq1[ti] = *(const s16x8*)(lQ + row*64 + (((kg+4)^s7)*8));
  }
  const float* crow = cr + (size_t)bh*T_;
  const float* srow = sr + (size_t)bh*T_;
  f32x2 cjlo[4], cjhi[4], sjlo[4], sjhi[4];
#pragma unroll
  for (int s = 0; s < 4; ++s) {
    float4 cj = *(const float4*)(crow + jb*128 + wj*64 + s*16 + kg*4);
    float4 sj = *(const float4*)(srow + jb*128 + wj*64 + s*16 + kg*4);
    cjlo[s][0]=cj.x; cjlo[s][1]=cj.y; cjhi[s][0]=cj.z; cjhi[s][1]=cj.w;
    sjlo[s][0]=sj.x; sjlo[s][1]=sj.y; sjhi[s][0]=sj.z; sjhi[s][1]=sj.w;
  }
  __syncthreads();                       // all LDS reads done -> safe to reuse

  // ---- phase B: compute 16 chains, ds_write packed fp8 into lJ (swizzled)
  f32x2 Cp2[4], Sp2[4], Ep2[4];
#pragma unroll
  for (int ti = 0; ti < 4; ++ti) {
    Cp2[ti][0]=0.f; Cp2[ti][1]=0.f; Sp2[ti][0]=0.f; Sp2[ti][1]=0.f; Ep2[ti][0]=0.f; Ep2[ti][1]=0.f;
  }
#pragma unroll
  for (int ti = 0; ti < 4; ++ti) {
    const int row = wi*64 + ti*16 + lr;
    const int rx = row & 7;
#pragma unroll
    for (int s = 0; s < 4; ++s) {
      f32x4 dd; dd[0]=0.f; dd[1]=0.f; dd[2]=0.f; dd[3]=0.f;
      dd = __builtin_amdgcn_mfma_f32_16x16x32_bf16(ak0[s], bq0[ti], dd, 0, 0, 0);
      dd = __builtin_amdgcn_mfma_f32_16x16x32_bf16(ak1[s], bq1[ti], dd, 0, 0, 0);
      // Q pre-scaled by log2e: dd = logit*log2e -> exp2 = exp(logit)
      float e0 = exp2f(dd[0]), e1 = exp2f(dd[1]);
      float e2 = exp2f(dd[2]), e3 = exp2f(dd[3]);
      unsigned int p = 0;
      p = __builtin_amdgcn_cvt_pk_fp8_f32(e0, e1, p, false);
      p = __builtin_amdgcn_cvt_pk_fp8_f32(e2, e3, p, true);
      // logical byte col = wj*64+s*16+kg*4 ; 16B-block (wj*4+s) XOR-swizzled
      *(unsigned int*)(lJ + row*128 + (((wj*4 + s) ^ rx) << 4) + kg*4) = p;
      f32x2 elo; elo[0]=e0; elo[1]=e1;
      f32x2 ehi; ehi[0]=e2; ehi[1]=e3;
      Cp2[ti] += elo*cjlo[s] + ehi*cjhi[s];
      Sp2[ti] += elo*sjlo[s] + ehi*sjhi[s];
      Ep2[ti] += elo + ehi;
    }
  }
  float Cp[4], Sp[4], Ep[4];
#pragma unroll
  for (int ti = 0; ti < 4; ++ti) {
    Cp[ti] = Cp2[ti][0] + Cp2[ti][1];
    Sp[ti] = Sp2[ti][0] + Sp2[ti][1];
    Ep[ti] = Ep2[ti][0] + Ep2[ti][1];
  }
  // kg-reduce (this wave's 64 j) -> lRed[wj][i_local][3]
#pragma unroll
  for (int m = 16; m < 64; m <<= 1)
#pragma unroll
    for (int ti = 0; ti < 4; ++ti) {
      Cp[ti] += __shfl_xor(Cp[ti], m);
      Sp[ti] += __shfl_xor(Sp[ti], m);
      Ep[ti] += __shfl_xor(Ep[ti], m);
    }
  if (kg == 0) {
#pragma unroll
    for (int ti = 0; ti < 4; ++ti) {
      int i = wi*64 + ti*16 + lr;
      lRed[(wj*128 + i)*3 + 0] = Cp[ti];
      lRed[(wj*128 + i)*3 + 1] = Sp[ti];
      lRed[(wj*128 + i)*3 + 2] = Ep[ti];
    }
  }
  __syncthreads();                       // lJ + lRed complete

  // ---- phase C: fat stores — each wave-instr = 8 full rows x 128 B contig
#pragma unroll
  for (int it = 0; it < 4; ++it) {
    int row = it*32 + (t >> 3);
    int blk = t & 7;
    uint4 v = *(const uint4*)(lJ + row*128 + (((blk ^ (row & 7)) << 4)));
    *(uint4*)(J + ((size_t)(bh*T_ + i0 + row))*T_ + jb*128 + blk*16) = v;
  }
  if (parts != nullptr && t < 128) {
    float C = lRed[t*3+0] + lRed[(128+t)*3+0];
    float S = lRed[t*3+1] + lRed[(128+t)*3+1];
    float E = lRed[t*3+2] + lRed[(128+t)*3+2];
    const size_t N = (size_t)BH_*T_;
    size_t rowg = (size_t)bh*T_ + i0 + t;
    parts[(0*16 + jb)*N + rowg] = C;
    parts[(1*16 + jb)*N + rowg] = S;
    parts[(2*16 + jb)*N + rowg] = E;
  }
}

// finalize step 1: sum 16 chunk-partials, update phase, emit cos/sin
__global__ void finalize1(const float* __restrict__ parts,
                          const float* __restrict__ cr, const float* __restrict__ sr,
                          float* __restrict__ cw, float* __restrict__ sw,
                          float* __restrict__ ph, const float* __restrict__ omega)
{
  int idx = blockIdx.x*256 + threadIdx.x;   // over BH*T
  const size_t N = (size_t)BH_*T_;
  float C = 0.f, S = 0.f, E = 0.f;
#pragma unroll
  for (int c = 0; c < 16; ++c) {
    C += parts[(0*16 + c)*N + idx];
    S += parts[(1*16 + c)*N + idx];
    E += parts[(2*16 + c)*N + idx];
  }
  int bh = idx >> 11;
  float si = sr[idx], ci = cr[idx];
  float coupling = (si*C - ci*S) / E;
  float pn = ph[idx] + DT_*(omega[bh & 15] + coupling);
  pn = fmodf(pn, TWO_PI_F);
  if (pn < 0.f) pn += TWO_PI_F;             // numpy mod semantics
  ph[idx] = pn;
  cw[idx] = __cosf(pn);
  sw[idx] = __sinf(pn);
}

// ---------------------------------------------------------------------------
// j_step2: streaming Kuramoto step.  8 rows/wave, uint4 J loads, f32x2
// accumulators -> v_pk_fma_f32; cos/sin double-buffered, epilogue writes
// next step's cos/sin.
// ---------------------------------------------------------------------------
__global__ __launch_bounds__(256)
void j_step2(const unsigned char* __restrict__ J,
             const float* __restrict__ cr, const float* __restrict__ sr,
             float* __restrict__ cw, float* __restrict__ sw,
             float* __restrict__ ph, const float* __restrict__ omega)
{
  const int wv = threadIdx.x >> 6, lane = threadIdx.x & 63;
  const int r0 = (blockIdx.x*4 + wv)*JROWS;  // 8 rows per wave, rows = bh*T+t
  const int bh = r0 >> 11;
  const float4* c4 = (const float4*)(cr + (size_t)bh*T_);
  const float4* s4 = (const float4*)(sr + (size_t)bh*T_);

  f32x2 C2[JROWS], S2[JROWS], E2[JROWS];
#pragma unroll
  for (int r = 0; r < JROWS; ++r) {
    C2[r][0]=0.f; C2[r][1]=0.f; S2[r][0]=0.f; S2[r][1]=0.f; E2[r][0]=0.f; E2[r][1]=0.f;
  }

#pragma unroll
  for (int k = 0; k < 2; ++k) {
    int idx = k*64 + lane;                   // uint4 index (16 fp8 = 16 j)
    f32x2 clo[4], chi[4], slo[4], shi[4];
#pragma unroll
    for (int q = 0; q < 4; ++q) {
      float4 cv = c4[idx*4+q], sv = s4[idx*4+q];
      clo[q][0]=cv.x; clo[q][1]=cv.y; chi[q][0]=cv.z; chi[q][1]=cv.w;
      slo[q][0]=sv.x; slo[q][1]=sv.y; shi[q][0]=sv.z; shi[q][1]=sv.w;
    }
#pragma unroll
    for (int row = 0; row < JROWS; ++row) {
      uint4 jv = *(const uint4*)(J + (size_t)(r0+row)*T_ + (size_t)idx*16);
#pragma unroll
      for (int q = 0; q < 4; ++q) {
        unsigned int wq_ = (q==0)?jv.x:(q==1)?jv.y:(q==2)?jv.z:jv.w;
        f32x2 lo = __builtin_amdgcn_cvt_pk_f32_fp8(wq_, false);
        f32x2 hi = __builtin_amdgcn_cvt_pk_f32_fp8(wq_, true);
        C2[row] += lo*clo[q] + hi*chi[q];
        S2[row] += lo*slo[q] + hi*shi[q];
        E2[row] += lo + hi;
      }
    }
  }

  float C[JROWS], S[JROWS], E[JROWS];
#pragma unroll
  for (int r = 0; r < JROWS; ++r) { C[r]=C2[r][0]+C2[r][1]; S[r]=S2[r][0]+S2[r][1]; E[r]=E2[r][0]+E2[r][1]; }

#pragma unroll
  for (int m = 1; m < 64; m <<= 1) {
#pragma unroll
    for (int row = 0; row < JROWS; ++row) {
      C[row] += __shfl_xor(C[row], m);
      S[row] += __shfl_xor(S[row], m);
      E[row] += __shfl_xor(E[row], m);
    }
  }

  if (lane < JROWS) {
    float Cc = C[0], Ss = S[0], Ee = E[0];
#pragma unroll
    for (int r = 1; r < JROWS; ++r)
      if (lane == r) { Cc = C[r]; Ss = S[r]; Ee = E[r]; }
    int pidx = r0 + lane;
    float si = sr[pidx], ci = cr[pidx];
    float om = omega[bh & 15];
    float coupling = (si*Cc - ci*Ss) / Ee;
    float pn = ph[pidx] + DT_*(om + coupling);
    pn = fmodf(pn, TWO_PI_F);
    if (pn < 0.f) pn += TWO_PI_F;
    ph[pidx] = pn;
    cw[pidx] = __cosf(pn);
    sw[pidx] = __sinf(pn);
  }
}

// vmod: V *= cos(phase_final) in bf16 (reads final cos buffer)
__global__ void vmod2(unsigned short* __restrict__ V, const float* __restrict__ cfin)
{
  int idx = blockIdx.x*256 + threadIdx.x;    // over M_*D_/8
  int row = idx >> 7;           // b*T + t
  int g = idx & 127;
  int h = g >> 3;               // 8 s16x8 groups per head
  int b = row >> 11, tt = row & 2047;
  float c = cfin[((size_t)(b*H_ + h))*T_ + tt];
  s16x8 v = *(s16x8*)(V + (size_t)idx*8);
  s16x8 o;
#pragma unroll
  for (int e = 0; e < 8; ++e) {
    float f = __uint_as_float(((unsigned int)(unsigned short)v[e]) << 16);
    o[e] = (short)f2bf(f * c);
  }
  *(s16x8*)(V + (size_t)idx*8) = o;
}

// ---------------------------------------------------------------------------
extern "C" void kernel_launch(void* const* d_in, const int* in_sizes, int n_in,
                              void* d_out, int out_size, void* d_ws, size_t ws_size,
                              hipStream_t stream)
{
  const float* x     = (const float*)d_in[0];
  const float* Wq    = (const float*)d_in[1];
  const float* Wk    = (const float*)d_in[2];
  const float* Wv    = (const float*)d_in[3];
  const float* Wo    = (const float*)d_in[4];
  const float* omega = (const float*)d_in[5];
  float* out = (float*)d_out;

  // workspace carve (J aliases dead xb/wqb/wkb/wvb; parts last, ws-guarded)
  char* w = (char*)d_ws;
  unsigned short* Qb  = (unsigned short*)w; w += (size_t)M_*D_*2;   // bf16, pre-scaled (1/8)*log2e
  unsigned short* Kb  = (unsigned short*)w; w += (size_t)M_*D_*2;
  unsigned short* Vb  = (unsigned short*)w; w += (size_t)M_*D_*2;   // bf16 V (vmod in place)
  unsigned short* wob = (unsigned short*)w; w += (size_t)D_*D_*2;
  float* ph   = (float*)w; w += (size_t)BH_*T_*4;
  float* csb[2]; float* snb[2];
  csb[0] = (float*)w; w += (size_t)BH_*T_*4;
  snb[0] = (float*)w; w += (size_t)BH_*T_*4;
  csb[1] = (float*)w; w += (size_t)BH_*T_*4;
  snb[1] = (float*)w; w += (size_t)BH_*T_*4;
  float* V01 = (float*)w; w += (size_t)M_*32*4;                     // 0.5 MiB
  unsigned char* J = (unsigned char*)w; w += (size_t)BH_*T_*T_;     // 128 MiB
  float* parts = (float*)w; w += (size_t)3*16*BH_*T_*4;             // 12.6 MiB
  const bool fuse = (ws_size >= (size_t)(w - (char*)d_ws));
  // aliased into J's head (dead once build_t runs):
  unsigned short* xb  = (unsigned short*)J;                         // 8 MiB
  unsigned short* wqb = (unsigned short*)(J + (size_t)M_*D_*2);
  unsigned short* wkb = wqb + (size_t)D_*D_;
  unsigned short* wvb = wkb + (size_t)D_*D_;

  conv_all<<<4096, 256, 0, stream>>>(x, Wq, Wk, Wv, Wo, xb, wqb, wkb, wvb, wob);

  gemm_qkv<<<dim3(M_/128, D_/128, 3), 256, 0, stream>>>(xb, wqb, wkb, wvb, Qb, Kb, Vb);

  v01_kernel<<<M_/4, 256, 0, stream>>>(x, Wv, V01);
  phase_init2<<<BH_*T_/256, 256, 0, stream>>>(V01, ph, csb[0], snb[0]);

  // one-shot J materialization + (if ws allows) fused step-1 partials
  build_t<<<dim3(T_/128, T_/128, BH_), 256, 0, stream>>>(
      Qb, Kb, J, csb[0], snb[0], fuse ? parts : nullptr);

  int s0;
  if (fuse) {
    finalize1<<<BH_*T_/256, 256, 0, stream>>>(parts, csb[0], snb[0], csb[1], snb[1], ph, omega);
    s0 = 1;
  } else {
    s0 = 0;
  }
  for (int s = s0; s < NSTEP; ++s)
    j_step2<<<BH_*T_/(4*JROWS), 256, 0, stream>>>(J, csb[s&1], snb[s&1],
                                                  csb[(s+1)&1], snb[(s+1)&1], ph, omega);

  vmod2<<<M_*D_/8/256, 256, 0, stream>>>(Vb, csb[NSTEP&1]);
  gemm_o<<<dim3(M_/64, D_/128), 256, 0, stream>>>(Vb, wob, out, x);
}

// Round 15
// 276.500 us; speedup vs baseline: 1.0431x; 1.0431x over previous
//
#include <hip/hip_runtime.h>
#include <hip/hip_bf16.h>

#define B_    2
#define T_    2048
#define D_    1024
#define H_    16
#define DK_   64
#define BH_   (B_*H_)
#define M_    (B_*T_)        // 4096 GEMM rows
#define NSTEP 5
#define DT_   0.1f
#define TWO_PI_F 6.28318530717958647692f
#define JROWS 8
#define LOG2E_F 1.44269504088896340736f

typedef __attribute__((ext_vector_type(8))) short s16x8;   // 8 bf16 (4 VGPRs)
typedef __attribute__((ext_vector_type(4))) float f32x4;
typedef __attribute__((ext_vector_type(2))) float f32x2;

__device__ __forceinline__ unsigned short f2bf(float f) {
  unsigned int u = __float_as_uint(f);
  u += 0x7FFFu + ((u >> 16) & 1u);       // round-to-nearest-even
  return (unsigned short)(u >> 16);
}

__device__ __forceinline__ void gload_lds16(const void* g, void* l) {
  __builtin_amdgcn_global_load_lds(
      (const __attribute__((address_space(1))) unsigned int*)g,
      (__attribute__((address_space(3))) unsigned int*)l, 16, 0, 0);
}

// ---------------------------------------------------------------------------
// f32 -> bf16 conversion, all 5 tensors in one launch.
// ---------------------------------------------------------------------------
__device__ __forceinline__ void conv8(const float* in, unsigned short* out, int i) {
  const float4* p = (const float4*)in + (size_t)i*2;
  float4 a = p[0], b = p[1];
  s16x8 o;
  o[0]=(short)f2bf(a.x); o[1]=(short)f2bf(a.y); o[2]=(short)f2bf(a.z); o[3]=(short)f2bf(a.w);
  o[4]=(short)f2bf(b.x); o[5]=(short)f2bf(b.y); o[6]=(short)f2bf(b.z); o[7]=(short)f2bf(b.w);
  *(s16x8*)(out + (size_t)i*8) = o;
}

__global__ void conv_all(const float* __restrict__ x,
                         const float* __restrict__ wq, const float* __restrict__ wk,
                         const float* __restrict__ wv, const float* __restrict__ wo,
                         unsigned short* __restrict__ xb,
                         unsigned short* __restrict__ oq, unsigned short* __restrict__ ok,
                         unsigned short* __restrict__ ov, unsigned short* __restrict__ oo)
{
  int bid = blockIdx.x;
  if (bid < 2048) {                       // x: 4M elements
    conv8(x, xb, bid*256 + threadIdx.x);
  } else {                                // weights: 1M each, 512 blocks each
    int r = bid - 2048;
    int z = r >> 9, lb = r & 511;
    const float* in = (z==0)?wq:(z==1)?wk:(z==2)?wv:wo;
    unsigned short* out = (z==0)?oq:(z==1)?ok:(z==2)?ov:oo;
    conv8(in, out, lb*256 + threadIdx.x);
  }
}

// ---------------------------------------------------------------------------
// bf16 GEMM (m97 structure): BMx128 tile, BK=64, 4 waves, global_load_lds(16B),
// XOR-swizzled LDS (linear dest + pre-swizzled global src + swizzled ds_read).
// Y[m,n] = sum_k A[m,k]*W[n,k].  MODE 0: bf16(Y*scale). MODE 2: f32(Y)+res.
// ---------------------------------------------------------------------------
template<int BM, int MODE>
__device__ __forceinline__ void gemm_body(const unsigned short* __restrict__ A,
    const unsigned short* __restrict__ W, void* __restrict__ outp,
    const float* __restrict__ res, float scale, int m0, int n0)
{
  constexpr int MF = BM/32;               // fragment rows per wave
  __shared__ unsigned short lA[BM*64];
  __shared__ unsigned short lB[128*64];
  const int t = threadIdx.x, wv = t >> 6, lane = t & 63;
  const int wm = wv >> 1, wn = wv & 1;
  const int lr = lane & 15, kg = lane >> 4;
  const int lrow = lane >> 3, sch = (lane & 7) ^ lrow;   // src pre-swizzle

  f32x4 acc[MF][4];
#pragma unroll
  for (int i = 0; i < MF; ++i)
#pragma unroll
    for (int j = 0; j < 4; ++j) { acc[i][j][0]=0.f; acc[i][j][1]=0.f; acc[i][j][2]=0.f; acc[i][j][3]=0.f; }

  for (int kt = 0; kt < 1024; kt += 64) {
#pragma unroll
    for (int ii = 0; ii < BM/32; ++ii) {
      const int inst = wv*(BM/32) + ii;
      const int row  = inst*8 + lrow;
      gload_lds16(A + (size_t)(m0+row)*1024 + kt + sch*8, lA + inst*512);
    }
#pragma unroll
    for (int ii = 0; ii < 4; ++ii) {
      const int inst = wv*4 + ii;
      const int row  = inst*8 + lrow;
      gload_lds16(W + (size_t)(n0+row)*1024 + kt + sch*8, lB + inst*512);
    }
    __syncthreads();

    s16x8 a0[MF], a1[MF], b0[4], b1[4];
#pragma unroll
    for (int mf = 0; mf < MF; ++mf) {
      int row = wm*(BM/2) + mf*16 + lr, s7 = row & 7;
      a0[mf] = *(const s16x8*)(lA + row*64 + ((kg^s7)*8));
      a1[mf] = *(const s16x8*)(lA + row*64 + (((kg+4)^s7)*8));
    }
#pragma unroll
    for (int nf = 0; nf < 4; ++nf) {
      int row = wn*64 + nf*16 + lr, s7 = row & 7;
      b0[nf] = *(const s16x8*)(lB + row*64 + ((kg^s7)*8));
      b1[nf] = *(const s16x8*)(lB + row*64 + (((kg+4)^s7)*8));
    }
#pragma unroll
    for (int mf = 0; mf < MF; ++mf)
#pragma unroll
      for (int nf = 0; nf < 4; ++nf) {
        acc[mf][nf] = __builtin_amdgcn_mfma_f32_16x16x32_bf16(a0[mf], b0[nf], acc[mf][nf], 0,0,0);
        acc[mf][nf] = __builtin_amdgcn_mfma_f32_16x16x32_bf16(a1[mf], b1[nf], acc[mf][nf], 0,0,0);
      }
    __syncthreads();
  }

#pragma unroll
  for (int mf = 0; mf < MF; ++mf)
#pragma unroll
    for (int nf = 0; nf < 4; ++nf)
#pragma unroll
      for (int r = 0; r < 4; ++r) {
        int grow = m0 + wm*(BM/2) + mf*16 + kg*4 + r;   // C/D: row=(lane>>4)*4+reg
        int gcol = n0 + wn*64 + nf*16 + lr;             //      col=lane&15
        size_t o = (size_t)grow*1024 + gcol;
        float v = acc[mf][nf][r];
        if (MODE == 0) ((unsigned short*)outp)[o] = f2bf(v*scale);
        else           ((float*)outp)[o] = v + res[o];
      }
}

__global__ __launch_bounds__(256)
void gemm_qkv(const unsigned short* __restrict__ xb,
              const unsigned short* __restrict__ wq, const unsigned short* __restrict__ wk,
              const unsigned short* __restrict__ wv_,
              unsigned short* __restrict__ Qb, unsigned short* __restrict__ Kb,
              unsigned short* __restrict__ Vb)
{
  const int z = blockIdx.z;
  const unsigned short* W = (z==0)?wq:((z==1)?wk:wv_);
  unsigned short* O = (z==0)?Qb:((z==1)?Kb:Vb);
  // z==0: Q pre-scaled by (1/8)*log2(e) so build_t can use raw v_exp_f32.
  const float scale = (z==0) ? 0.125f*LOG2E_F : 1.0f;
  gemm_body<128,0>(xb, W, O, nullptr, scale, blockIdx.x*128, blockIdx.y*128);
}

__global__ __launch_bounds__(256)
void gemm_o(const unsigned short* __restrict__ Ab, const unsigned short* __restrict__ wo,
            float* __restrict__ out, const float* __restrict__ x)
{
  gemm_body<64,2>(Ab, wo, out, x, 1.0f, blockIdx.x*64, blockIdx.y*128);
}

// ---------------------------------------------------------------------------
// v01: exact f32 dot products, coalesced (k on lane axis) — r13, confirmed.
// ---------------------------------------------------------------------------
__global__ __launch_bounds__(256)
void v01_kernel(const float* __restrict__ x, const float* __restrict__ Wv,
                float* __restrict__ V01)
{
  const int wv = threadIdx.x >> 6, lane = threadIdx.x & 63;
  const int row = blockIdx.x*4 + wv;
  const float4* xr = (const float4*)(x + (size_t)row*1024);
  float4 xv[4];
#pragma unroll
  for (int p = 0; p < 4; ++p) xv[p] = xr[lane + p*64];

  float part[32];
#pragma unroll
  for (int c = 0; c < 32; ++c) {
    const int wcol = (c >> 1)*DK_ + (c & 1);
    const float4* wr = (const float4*)(Wv + (size_t)wcol*1024);
    float a = 0.f;
#pragma unroll
    for (int p = 0; p < 4; ++p) {
      float4 bv = wr[lane + p*64];
      a += xv[p].x*bv.x + xv[p].y*bv.y + xv[p].z*bv.z + xv[p].w*bv.w;
    }
    part[c] = a;
  }
#pragma unroll
  for (int c = 0; c < 32; ++c)
#pragma unroll
    for (int m = 1; m < 64; m <<= 1)
      part[c] += __shfl_xor(part[c], m);

  float outv = part[0];
#pragma unroll
  for (int c = 1; c < 32; ++c)
    if ((lane & 31) == c) outv = part[c];
  if (lane < 32) V01[(size_t)row*32 + lane] = outv;
}

// phase init + exact cos/sin (cos(atan2(a,c)) = c/r, sin = a/r)
__global__ void phase_init2(const float* __restrict__ V01, float* __restrict__ ph,
                            float* __restrict__ cw, float* __restrict__ sw)
{
  int idx = blockIdx.x*256 + threadIdx.x;  // over B*H*T
  int tt = idx & (T_-1);
  int bh = idx >> 11;
  int b = bh >> 4, h = bh & 15;
  float a = V01[((size_t)(b*T_ + tt))*32 + h*2 + 0];
  float c = V01[((size_t)(b*T_ + tt))*32 + h*2 + 1] + 1e-8f;
  ph[idx] = atan2f(a, c);
  float r = fmaxf(sqrtf(a*a + c*c), 1e-30f);
  cw[idx] = c / r;
  sw[idx] = a / r;
}

// ---------------------------------------------------------------------------
// build_t: one-shot J = fp8(exp(q.k/8)) with LDS-transposed fat stores +
// fused step-1 C/S/E (r11/r13 confirmed).  r15 fix: r14's exp2f pulled in
// the PRECISE ocml path (range branch + ldexp, ~10 inst) -> VALUBusy 54->65%
// and +10us.  __builtin_amdgcn_exp2f is the bare v_exp_f32 -- with the
// log2e pre-scale this is strictly fewer VALU ops than r13's __expf.
// ---------------------------------------------------------------------------
__global__ __launch_bounds__(256)
void build_t(const unsigned short* __restrict__ Qb, const unsigned short* __restrict__ Kb,
             unsigned char* __restrict__ J,
             const float* __restrict__ cr, const float* __restrict__ sr,
             float* __restrict__ parts)
{
  __shared__ unsigned char lds[32768];
  unsigned short* lK = (unsigned short*)lds;             // phase A: 16 KB
  unsigned short* lQ = (unsigned short*)(lds + 16384);   // phase A: 16 KB
  unsigned char*  lJ = lds;                              // phase B: 16 KB
  float* lRed = (float*)(lds + 16384);                   // phase B: 3 KB (in dead lQ)

  const int ib = blockIdx.x, jb = blockIdx.y, bh = blockIdx.z;
  const int b = bh >> 4, h = bh & 15;
  const int t = threadIdx.x, wv = t >> 6, lane = t & 63;
  const int wj = wv >> 1, wi = wv & 1;
  const int lr = lane & 15, kg = lane >> 4;
  const int lrow = lane >> 3, sch = (lane & 7) ^ lrow;   // src pre-swizzle
  const int i0 = ib*128;

  const unsigned short* Kbase = Kb + (size_t)b*T_*D_ + h*DK_;
  const unsigned short* Qbase = Qb + (size_t)b*T_*D_ + h*DK_;

  // ---- phase A: stage K (j-tile) and Q (i-tile)
#pragma unroll
  for (int ii = 0; ii < 4; ++ii) {
    const int inst = wv*4 + ii;
    const int row  = inst*8 + lrow;
    gload_lds16(Kbase + (size_t)(jb*128 + row)*D_ + sch*8, lK + inst*512);
    gload_lds16(Qbase + (size_t)(i0 + row)*D_ + sch*8, lQ + inst*512);
  }
  __syncthreads();

  // all fragment reads upfront (LDS freed for reuse after next barrier)
  s16x8 ak0[4], ak1[4], bq0[4], bq1[4];
#pragma unroll
  for (int s = 0; s < 4; ++s) {
    int row = wj*64 + s*16 + lr, s7 = row & 7;
    ak0[s] = *(const s16x8*)(lK + row*64 + ((kg^s7)*8));
    ak1[s] = *(const s16x8*)(lK + row*64 + (((kg+4)^s7)*8));
  }
#pragma unroll
  for (int ti = 0; ti < 4; ++ti) {
    int row = wi*64 + ti*16 + lr, s7 = row & 7;
    bq0[ti] = *(const s16x8*)(lQ + row*64 + ((kg^s7)*8));
    bq1[ti] = *(const s16x8*)(lQ + row*64 + (((kg+4)^s7)*8));
  }
  const float* crow = cr + (size_t)bh*T_;
  const float* srow = sr + (size_t)bh*T_;
  f32x2 cjlo[4], cjhi[4], sjlo[4], sjhi[4];
#pragma unroll
  for (int s = 0; s < 4; ++s) {
    float4 cj = *(const float4*)(crow + jb*128 + wj*64 + s*16 + kg*4);
    float4 sj = *(const float4*)(srow + jb*128 + wj*64 + s*16 + kg*4);
    cjlo[s][0]=cj.x; cjlo[s][1]=cj.y; cjhi[s][0]=cj.z; cjhi[s][1]=cj.w;
    sjlo[s][0]=sj.x; sjlo[s][1]=sj.y; sjhi[s][0]=sj.z; sjhi[s][1]=sj.w;
  }
  __syncthreads();                       // all LDS reads done -> safe to reuse

  // ---- phase B: compute 16 chains, ds_write packed fp8 into lJ (swizzled)
  f32x2 Cp2[4], Sp2[4], Ep2[4];
#pragma unroll
  for (int ti = 0; ti < 4; ++ti) {
    Cp2[ti][0]=0.f; Cp2[ti][1]=0.f; Sp2[ti][0]=0.f; Sp2[ti][1]=0.f; Ep2[ti][0]=0.f; Ep2[ti][1]=0.f;
  }
#pragma unroll
  for (int ti = 0; ti < 4; ++ti) {
    const int row = wi*64 + ti*16 + lr;
    const int rx = row & 7;
#pragma unroll
    for (int s = 0; s < 4; ++s) {
      f32x4 dd; dd[0]=0.f; dd[1]=0.f; dd[2]=0.f; dd[3]=0.f;
      dd = __builtin_amdgcn_mfma_f32_16x16x32_bf16(ak0[s], bq0[ti], dd, 0, 0, 0);
      dd = __builtin_amdgcn_mfma_f32_16x16x32_bf16(ak1[s], bq1[ti], dd, 0, 0, 0);
      // Q pre-scaled by log2e: raw v_exp_f32 (bare exp2) = exp(logit)
      float e0 = __builtin_amdgcn_exp2f(dd[0]), e1 = __builtin_amdgcn_exp2f(dd[1]);
      float e2 = __builtin_amdgcn_exp2f(dd[2]), e3 = __builtin_amdgcn_exp2f(dd[3]);
      unsigned int p = 0;
      p = __builtin_amdgcn_cvt_pk_fp8_f32(e0, e1, p, false);
      p = __builtin_amdgcn_cvt_pk_fp8_f32(e2, e3, p, true);
      // logical byte col = wj*64+s*16+kg*4 ; 16B-block (wj*4+s) XOR-swizzled
      *(unsigned int*)(lJ + row*128 + (((wj*4 + s) ^ rx) << 4) + kg*4) = p;
      f32x2 elo; elo[0]=e0; elo[1]=e1;
      f32x2 ehi; ehi[0]=e2; ehi[1]=e3;
      Cp2[ti] += elo*cjlo[s] + ehi*cjhi[s];
      Sp2[ti] += elo*sjlo[s] + ehi*sjhi[s];
      Ep2[ti] += elo + ehi;
    }
  }
  float Cp[4], Sp[4], Ep[4];
#pragma unroll
  for (int ti = 0; ti < 4; ++ti) {
    Cp[ti] = Cp2[ti][0] + Cp2[ti][1];
    Sp[ti] = Sp2[ti][0] + Sp2[ti][1];
    Ep[ti] = Ep2[ti][0] + Ep2[ti][1];
  }
  // kg-reduce (this wave's 64 j) -> lRed[wj][i_local][3]
#pragma unroll
  for (int m = 16; m < 64; m <<= 1)
#pragma unroll
    for (int ti = 0; ti < 4; ++ti) {
      Cp[ti] += __shfl_xor(Cp[ti], m);
      Sp[ti] += __shfl_xor(Sp[ti], m);
      Ep[ti] += __shfl_xor(Ep[ti], m);
    }
  if (kg == 0) {
#pragma unroll
    for (int ti = 0; ti < 4; ++ti) {
      int i = wi*64 + ti*16 + lr;
      lRed[(wj*128 + i)*3 + 0] = Cp[ti];
      lRed[(wj*128 + i)*3 + 1] = Sp[ti];
      lRed[(wj*128 + i)*3 + 2] = Ep[ti];
    }
  }
  __syncthreads();                       // lJ + lRed complete

  // ---- phase C: fat stores — each wave-instr = 8 full rows x 128 B contig
#pragma unroll
  for (int it = 0; it < 4; ++it) {
    int row = it*32 + (t >> 3);
    int blk = t & 7;
    uint4 v = *(const uint4*)(lJ + row*128 + (((blk ^ (row & 7)) << 4)));
    *(uint4*)(J + ((size_t)(bh*T_ + i0 + row))*T_ + jb*128 + blk*16) = v;
  }
  if (parts != nullptr && t < 128) {
    float C = lRed[t*3+0] + lRed[(128+t)*3+0];
    float S = lRed[t*3+1] + lRed[(128+t)*3+1];
    float E = lRed[t*3+2] + lRed[(128+t)*3+2];
    const size_t N = (size_t)BH_*T_;
    size_t rowg = (size_t)bh*T_ + i0 + t;
    parts[(0*16 + jb)*N + rowg] = C;
    parts[(1*16 + jb)*N + rowg] = S;
    parts[(2*16 + jb)*N + rowg] = E;
  }
}

// finalize step 1: sum 16 chunk-partials, update phase, emit cos/sin
__global__ void finalize1(const float* __restrict__ parts,
                          const float* __restrict__ cr, const float* __restrict__ sr,
                          float* __restrict__ cw, float* __restrict__ sw,
                          float* __restrict__ ph, const float* __restrict__ omega)
{
  int idx = blockIdx.x*256 + threadIdx.x;   // over BH*T
  const size_t N = (size_t)BH_*T_;
  float C = 0.f, S = 0.f, E = 0.f;
#pragma unroll
  for (int c = 0; c < 16; ++c) {
    C += parts[(0*16 + c)*N + idx];
    S += parts[(1*16 + c)*N + idx];
    E += parts[(2*16 + c)*N + idx];
  }
  int bh = idx >> 11;
  float si = sr[idx], ci = cr[idx];
  float coupling = (si*C - ci*S) / E;
  float pn = ph[idx] + DT_*(omega[bh & 15] + coupling);
  pn = fmodf(pn, TWO_PI_F);
  if (pn < 0.f) pn += TWO_PI_F;             // numpy mod semantics
  ph[idx] = pn;
  cw[idx] = __cosf(pn);
  sw[idx] = __sinf(pn);
}

// ---------------------------------------------------------------------------
// j_step2: streaming Kuramoto step.  8 rows/wave, uint4 J loads, f32x2
// accumulators -> v_pk_fma_f32; cos/sin double-buffered, epilogue writes
// next step's cos/sin.
// ---------------------------------------------------------------------------
__global__ __launch_bounds__(256)
void j_step2(const unsigned char* __restrict__ J,
             const float* __restrict__ cr, const float* __restrict__ sr,
             float* __restrict__ cw, float* __restrict__ sw,
             float* __restrict__ ph, const float* __restrict__ omega)
{
  const int wv = threadIdx.x >> 6, lane = threadIdx.x & 63;
  const int r0 = (blockIdx.x*4 + wv)*JROWS;  // 8 rows per wave, rows = bh*T+t
  const int bh = r0 >> 11;
  const float4* c4 = (const float4*)(cr + (size_t)bh*T_);
  const float4* s4 = (const float4*)(sr + (size_t)bh*T_);

  f32x2 C2[JROWS], S2[JROWS], E2[JROWS];
#pragma unroll
  for (int r = 0; r < JROWS; ++r) {
    C2[r][0]=0.f; C2[r][1]=0.f; S2[r][0]=0.f; S2[r][1]=0.f; E2[r][0]=0.f; E2[r][1]=0.f;
  }

#pragma unroll
  for (int k = 0; k < 2; ++k) {
    int idx = k*64 + lane;                   // uint4 index (16 fp8 = 16 j)
    f32x2 clo[4], chi[4], slo[4], shi[4];
#pragma unroll
    for (int q = 0; q < 4; ++q) {
      float4 cv = c4[idx*4+q], sv = s4[idx*4+q];
      clo[q][0]=cv.x; clo[q][1]=cv.y; chi[q][0]=cv.z; chi[q][1]=cv.w;
      slo[q][0]=sv.x; slo[q][1]=sv.y; shi[q][0]=sv.z; shi[q][1]=sv.w;
    }
#pragma unroll
    for (int row = 0; row < JROWS; ++row) {
      uint4 jv = *(const uint4*)(J + (size_t)(r0+row)*T_ + (size_t)idx*16);
#pragma unroll
      for (int q = 0; q < 4; ++q) {
        unsigned int wq_ = (q==0)?jv.x:(q==1)?jv.y:(q==2)?jv.z:jv.w;
        f32x2 lo = __builtin_amdgcn_cvt_pk_f32_fp8(wq_, false);
        f32x2 hi = __builtin_amdgcn_cvt_pk_f32_fp8(wq_, true);
        C2[row] += lo*clo[q] + hi*chi[q];
        S2[row] += lo*slo[q] + hi*shi[q];
        E2[row] += lo + hi;
      }
    }
  }

  float C[JROWS], S[JROWS], E[JROWS];
#pragma unroll
  for (int r = 0; r < JROWS; ++r) { C[r]=C2[r][0]+C2[r][1]; S[r]=S2[r][0]+S2[r][1]; E[r]=E2[r][0]+E2[r][1]; }

#pragma unroll
  for (int m = 1; m < 64; m <<= 1) {
#pragma unroll
    for (int row = 0; row < JROWS; ++row) {
      C[row] += __shfl_xor(C[row], m);
      S[row] += __shfl_xor(S[row], m);
      E[row] += __shfl_xor(E[row], m);
    }
  }

  if (lane < JROWS) {
    float Cc = C[0], Ss = S[0], Ee = E[0];
#pragma unroll
    for (int r = 1; r < JROWS; ++r)
      if (lane == r) { Cc = C[r]; Ss = S[r]; Ee = E[r]; }
    int pidx = r0 + lane;
    float si = sr[pidx], ci = cr[pidx];
    float om = omega[bh & 15];
    float coupling = (si*Cc - ci*Ss) / Ee;
    float pn = ph[pidx] + DT_*(om + coupling);
    pn = fmodf(pn, TWO_PI_F);
    if (pn < 0.f) pn += TWO_PI_F;
    ph[pidx] = pn;
    cw[pidx] = __cosf(pn);
    sw[pidx] = __sinf(pn);
  }
}

// vmod: V *= cos(phase_final) in bf16 (reads final cos buffer)
__global__ void vmod2(unsigned short* __restrict__ V, const float* __restrict__ cfin)
{
  int idx = blockIdx.x*256 + threadIdx.x;    // over M_*D_/8
  int row = idx >> 7;           // b*T + t
  int g = idx & 127;
  int h = g >> 3;               // 8 s16x8 groups per head
  int b = row >> 11, tt = row & 2047;
  float c = cfin[((size_t)(b*H_ + h))*T_ + tt];
  s16x8 v = *(s16x8*)(V + (size_t)idx*8);
  s16x8 o;
#pragma unroll
  for (int e = 0; e < 8; ++e) {
    float f = __uint_as_float(((unsigned int)(unsigned short)v[e]) << 16);
    o[e] = (short)f2bf(f * c);
  }
  *(s16x8*)(V + (size_t)idx*8) = o;
}

// ---------------------------------------------------------------------------
extern "C" void kernel_launch(void* const* d_in, const int* in_sizes, int n_in,
                              void* d_out, int out_size, void* d_ws, size_t ws_size,
                              hipStream_t stream)
{
  const float* x     = (const float*)d_in[0];
  const float* Wq    = (const float*)d_in[1];
  const float* Wk    = (const float*)d_in[2];
  const float* Wv    = (const float*)d_in[3];
  const float* Wo    = (const float*)d_in[4];
  const float* omega = (const float*)d_in[5];
  float* out = (float*)d_out;

  // workspace carve (J aliases dead xb/wqb/wkb/wvb; parts last, ws-guarded)
  char* w = (char*)d_ws;
  unsigned short* Qb  = (unsigned short*)w; w += (size_t)M_*D_*2;   // bf16, pre-scaled (1/8)*log2e
  unsigned short* Kb  = (unsigned short*)w; w += (size_t)M_*D_*2;
  unsigned short* Vb  = (unsigned short*)w; w += (size_t)M_*D_*2;   // bf16 V (vmod in place)
  unsigned short* wob = (unsigned short*)w; w += (size_t)D_*D_*2;
  float* ph   = (float*)w; w += (size_t)BH_*T_*4;
  float* csb[2]; float* snb[2];
  csb[0] = (float*)w; w += (size_t)BH_*T_*4;
  snb[0] = (float*)w; w += (size_t)BH_*T_*4;
  csb[1] = (float*)w; w += (size_t)BH_*T_*4;
  snb[1] = (float*)w; w += (size_t)BH_*T_*4;
  float* V01 = (float*)w; w += (size_t)M_*32*4;                     // 0.5 MiB
  unsigned char* J = (unsigned char*)w; w += (size_t)BH_*T_*T_;     // 128 MiB
  float* parts = (float*)w; w += (size_t)3*16*BH_*T_*4;             // 12.6 MiB
  const bool fuse = (ws_size >= (size_t)(w - (char*)d_ws));
  // aliased into J's head (dead once build_t runs):
  unsigned short* xb  = (unsigned short*)J;                         // 8 MiB
  unsigned short* wqb = (unsigned short*)(J + (size_t)M_*D_*2);
  unsigned short* wkb = wqb + (size_t)D_*D_;
  unsigned short* wvb = wkb + (size_t)D_*D_;

  conv_all<<<4096, 256, 0, stream>>>(x, Wq, Wk, Wv, Wo, xb, wqb, wkb, wvb, wob);

  gemm_qkv<<<dim3(M_/128, D_/128, 3), 256, 0, stream>>>(xb, wqb, wkb, wvb, Qb, Kb, Vb);

  v01_kernel<<<M_/4, 256, 0, stream>>>(x, Wv, V01);
  phase_init2<<<BH_*T_/256, 256, 0, stream>>>(V01, ph, csb[0], snb[0]);

  // one-shot J materialization + (if ws allows) fused step-1 partials
  build_t<<<dim3(T_/128, T_/128, BH_), 256, 0, stream>>>(
      Qb, Kb, J, csb[0], snb[0], fuse ? parts : nullptr);

  int s0;
  if (fuse) {
    finalize1<<<BH_*T_/256, 256, 0, stream>>>(parts, csb[0], snb[0], csb[1], snb[1], ph, omega);
    s0 = 1;
  } else {
    s0 = 0;
  }
  for (int s = s0; s < NSTEP; ++s)
    j_step2<<<BH_*T_/(4*JROWS), 256, 0, stream>>>(J, csb[s&1], snb[s&1],
                                                  csb[(s+1)&1], snb[(s+1)&1], ph, omega);

  vmod2<<<M_*D_/8/256, 256, 0, stream>>>(Vb, csb[NSTEP&1]);
  gemm_o<<<dim3(M_/64, D_/128), 256, 0, stream>>>(Vb, wob, out, x);
}